// Round 10
// baseline (56.326 us; speedup 1.0000x reference)
//
#include <hip/hip_runtime.h>

typedef unsigned short u16;
typedef unsigned int u32;
typedef __bf16 bf16x8 __attribute__((ext_vector_type(8)));
typedef float f32x4 __attribute__((ext_vector_type(4)));
typedef u32 u32x4 __attribute__((ext_vector_type(4)));

#define AS1 __attribute__((address_space(1)))
#define AS3 __attribute__((address_space(3)))

// kT[t][c][r]  (fallback kernel layout)
__device__ __align__(16) u16 g_kT[27 * 64 * 64];
// kTr[((t*2+nh)*2+nt)*2+kb][lane][j] : per-lane-ordered repack -> every
// B-load is one fully-contiguous 1KB wave read (8 fully-used cachelines).
__device__ __align__(16) u16 g_kTr[27 * 8 * 512];

__device__ __forceinline__ u16 f2bf(float f) {
    unsigned int u = __float_as_uint(f);
    u += 0x7FFFu + ((u >> 16) & 1u);   // RNE
    return (u16)(u >> 16);
}

__device__ __forceinline__ u32 pack_bf(float a, float b) {
    u32 ua = __float_as_uint(a) + 0x8000u;
    u32 ub = __float_as_uint(b) + 0x8000u;
    return __builtin_amdgcn_perm(ub, ua, 0x07060302u);
}

// ---------------------------------------------------------------------------
// prep: blocks 0..26 build kT/kTr (+ fold self-connection into center tap);
//       blocks 27.. convert x fp32 -> bf16 (+ zero page in block 27).
// ---------------------------------------------------------------------------
__global__ __launch_bounds__(256) void prep(
    const float* __restrict__ Wsc0, const float* __restrict__ Wsc1,
    const float* __restrict__ w1, const float* __restrict__ w2,
    const float* __restrict__ w3, const float* __restrict__ w4,
    const float* __restrict__ x, u16* __restrict__ xb, u32* __restrict__ zp)
{
    const int tid = threadIdx.x;
    if (blockIdx.x < 27) {
        if (tid >= 64) return;
        const int t = blockIdx.x;
        const int c = tid;
        const int dx = t / 9 - 1, dy = (t / 3) % 3 - 1, dz = t % 3 - 1;
        const float d = sqrtf((float)(dx * dx + dy * dy + dz * dz));
        const float step = 1.5f / 9.0f;
        float emb[8];
#pragma unroll
        for (int k = 0; k < 8; ++k) {
            float diff = (d - (float)(k + 1) * step) / step;
            float q = diff * diff;
            emb[k] = (q < 1.0f) ? 1.14136f * expf(2.0f - 2.0f / (1.0f - q)) : 0.0f;
        }
        const float dn = fmaxf(d, 1e-12f);
        const float s3 = 1.7320508075688772f;
        const float sh1[3] = { s3 * dx / dn, s3 * dy / dn, s3 * dz / dn };
        const float alpha  = 0.17677669529663687f;
        const float alpha3 = alpha * 0.57735026918962576f;

        u16* outp = &g_kT[(t * 64 + c) * 64];
        const int base2 = ((t * 2 + (c >> 5)) * 2 + ((c >> 4) & 1)) * 2;
        const int l15c  = c & 15;
        auto put = [&](int r, float v) {
            u16 h = f2bf(v);
            outp[r] = h;
            g_kTr[(base2 + (r >> 5)) * 512 + (((r >> 3) & 3) * 16 + l15c) * 8 + (r & 7)] = h;
        };

        if (c < 16) {
            const int o = c;
#pragma unroll
            for (int i = 0; i < 16; ++i) {
                float W1 = 0.f, W4 = 0.f;
#pragma unroll
                for (int k = 0; k < 8; ++k) {
                    W1 += emb[k] * w1[k * 256 + i * 16 + o];
                    W4 += emb[k] * w4[k * 256 + i * 16 + o];
                }
                W1 *= (1.0f / 27.0f); W4 *= (1.0f / 27.0f);
                float v0 = alpha * W1;
                if (t == 13) v0 += 0.25f * Wsc0[i * 16 + o];
                put(i, v0);
                const float base = alpha3 * W4;
#pragma unroll
                for (int m = 0; m < 3; ++m) put(16 + 3 * i + m, base * sh1[m]);
            }
        } else {
            const int o = (c - 16) / 3, nc = (c - 16) % 3;
#pragma unroll
            for (int i = 0; i < 16; ++i) {
                float W2 = 0.f, W3 = 0.f;
#pragma unroll
                for (int k = 0; k < 8; ++k) {
                    W2 += emb[k] * w2[k * 256 + i * 16 + o];
                    W3 += emb[k] * w3[k * 256 + i * 16 + o];
                }
                W2 *= (1.0f / 27.0f); W3 *= (1.0f / 27.0f);
                put(i, alpha * W2 * sh1[nc]);
#pragma unroll
                for (int m = 0; m < 3; ++m) {
                    float v = (m == nc) ? alpha * W3 : 0.0f;
                    if (t == 13 && m == nc) v += 0.25f * Wsc1[i * 16 + o];
                    put(16 + 3 * i + m, v);
                }
            }
        }
    } else {
        const int bid2 = blockIdx.x - 27;
        if (bid2 == 0) {
            u32x4 z = {0u, 0u, 0u, 0u};
            *reinterpret_cast<u32x4*>(zp + tid * 4) = z;   // 4KB zero page
        }
        const size_t base = ((size_t)bid2 * 256 + tid) * 8;
        const float4* s = reinterpret_cast<const float4*>(x + base);
        float4 v0 = s[0], v1 = s[1];
        u32x4 p;
        p[0] = pack_bf(v0.x, v0.y); p[1] = pack_bf(v0.z, v0.w);
        p[2] = pack_bf(v1.x, v1.y); p[3] = pack_bf(v1.z, v1.w);
        *reinterpret_cast<u32x4*>(xb + base) = p;
    }
}

// ---------------------------------------------------------------------------
// v7: block = (b, X, 4y, 16z), 256 thr / 4 waves, 48KB LDS -> 3 blocks/CU
// (12 waves/CU, 3 waves/SIMD + cross-block phase stagger = overlap).
// Wave (yh 0..1, nh 0..1): M = 2y x 16z = 32, N = 32 ch.
// LDS: 3 planes x 16 chunks x 1KB; plane rows = yi*18 + zid (108 real + pad).
// ---------------------------------------------------------------------------
#define LDSW7 24576   // u16 count = 49152 B

#define ISSUE_B(s, t) \
  { const char* _p = bTr + (t) * 8192; \
    asm volatile("global_load_dwordx4 %0, %4, off\n\t" \
                 "global_load_dwordx4 %1, %4, off offset:1024\n\t" \
                 "global_load_dwordx4 %2, %4, off offset:2048\n\t" \
                 "global_load_dwordx4 %3, %4, off offset:3072" \
                 : "=&v"(B##s##0), "=&v"(B##s##1), "=&v"(B##s##2), "=&v"(B##s##3) \
                 : "v"(_p)); }

#define LOADA2(s, i0, i1, RCC) { \
  const int _r  = rbase + (RCC); \
  const int _o0 = _r * 128 + ((kg ^ (_r & 7)) << 4); \
  A##s##_##i0 = *reinterpret_cast<const bf16x8*>(abase + _o0); \
  A##s##_##i1 = *reinterpret_cast<const bf16x8*>(abase + (_o0 ^ 64)); }

// row = plane*128 + (dy + y')*18 + (l15 + dz); y' = yh*2 + yy
#define RCC7(T, YY) (((T)/9)*128 + ((((T)/3)%3) + (YY))*18 + ((T)%3))

#define LOAD_A4(s, T) \
  LOADA2(s, 0, 1, RCC7(T,0)) \
  LOADA2(s, 2, 3, RCC7(T,1))

#define WAITV(N) \
  asm volatile("s_waitcnt vmcnt(" #N ")" ::: "memory"); \
  __builtin_amdgcn_sched_barrier(0);

#define BARRIER() \
  asm volatile("s_barrier" ::: "memory"); \
  __builtin_amdgcn_sched_barrier(0);

#define BC(x) __builtin_bit_cast(bf16x8, x)
#define MF(b_, a_, c_) __builtin_amdgcn_mfma_f32_16x16x32_bf16(BC(b_), a_, c_, 0, 0, 0)

// 8 MFMAs: acc{yy}{nt} += B(kb,nt) x A(yy,kb); B: s0=nt0kb0 s1=nt0kb1 s2=nt1kb0 s3=nt1kb1
#define MFMA8(bs, as) \
  acc00 = MF(B##bs##0, A##as##_0, acc00); acc01 = MF(B##bs##2, A##as##_0, acc01); \
  acc10 = MF(B##bs##0, A##as##_2, acc10); acc11 = MF(B##bs##2, A##as##_2, acc11); \
  acc00 = MF(B##bs##1, A##as##_1, acc00); acc01 = MF(B##bs##3, A##as##_1, acc01); \
  acc10 = MF(B##bs##1, A##as##_3, acc10); acc11 = MF(B##bs##3, A##as##_3, acc11);

__global__ __launch_bounds__(256, 3) void conv_mfma7(
    const u16* __restrict__ xb, const u32* __restrict__ zp,
    float* __restrict__ out)
{
    __shared__ __align__(16) u16 xt[LDSW7];

    const int bid0 = blockIdx.x;
    const int bid  = (bid0 & 7) * 256 + (bid0 >> 3);   // XCD-contiguous panels
    const int b    = bid >> 9;
    const int X    = (bid >> 4) & 31;
    const int yg   = (bid >> 1) & 7;
    const int zg   = bid & 1;
    const int y0   = yg << 2;
    const int z0   = zg << 4;
    const int tid  = threadIdx.x;
    const int wv   = tid >> 6;       // 0..3
    const int lane = tid & 63;
    const int l15  = lane & 15;
    const int kg   = lane >> 4;
    const int yh   = wv >> 1;        // 0..1
    const int nh   = wv & 1;

    const char* bTr = (const char*)g_kTr + nh * 4096 + lane * 16;

    u32x4 B00, B01, B02, B03, B10, B11, B12, B13, B20, B21, B22, B23;
    bf16x8 A0_0, A0_1, A0_2, A0_3;
    bf16x8 A1_0, A1_1, A1_2, A1_3;

    // prologue: taps t1, t3 in flight before staging
    ISSUE_B(0, 1)
    ISSUE_B(1, 3)

    // ---- staging: 3 planes x 16 chunks x 1KB; 4 chunks/plane/wave ----
    {
        const int rloc = lane >> 3;
        const int swz  = (lane & 7) ^ rloc;
#pragma unroll
        for (int p = 0; p < 3; ++p) {
#pragma unroll
            for (int j = 0; j < 4; ++j) {
                const int cip = wv * 4 + j;          // 0..15
                const int rip = cip * 8 + rloc;      // 0..127 (108 real)
                const int yi  = rip / 18;
                const int zid = rip - yi * 18;
                const int xin = X + p - 1;
                const int yin = y0 + yi - 1;
                const int zin = z0 + zid - 1;
                const bool inb = (rip < 108) & ((unsigned)xin < 32u)
                               & ((unsigned)yin < 32u) & ((unsigned)zin < 32u);
                const u16* src = inb
                    ? xb + ((size_t)(((b * 32 + xin) * 32 + yin) * 32 + zin) * 64 + swz * 8)
                    : (const u16*)zp;
                __builtin_amdgcn_global_load_lds((const AS1 u32*)src,
                                                 (AS3 u32*)&xt[(p * 16 + cip) * 512],
                                                 16, 0, 0);
            }
        }
    }
    // outstanding: B1(4) B3(4) p0(4) p1(4) p2(4) = 20

    const char* abase = reinterpret_cast<const char*>(xt);
    const int rbase = yh * 36 + l15;

    const f32x4 z4 = {0.f, 0.f, 0.f, 0.f};
    f32x4 acc00 = z4, acc01 = z4, acc10 = z4, acc11 = z4;

    WAITV(8)      // retire B1,B3,p0 -> p1,p2 in flight
    BARRIER()     // plane 0 visible for all waves

    LOAD_A4(0, 1)
    ISSUE_B(2, 4)                             // [p1 p2 B4] = 12
    LOAD_A4(1, 3)            MFMA8(0, 0)      // t=1
    ISSUE_B(0, 5)                             // 16
    LOAD_A4(0, 4)            MFMA8(1, 1)      // t=3
    ISSUE_B(1, 7)                             // 20
    LOAD_A4(1, 5)  WAITV(8)  MFMA8(2, 0)      // t=4  (retire p1,p2,B4 -> B5,B7)
    ISSUE_B(2, 9)                             // 12
    BARRIER()     // planes 1,2 visible (every wave past its staging drain)
    LOAD_A4(0, 7)  WAITV(8)  MFMA8(0, 1)      // t=5  (retire B5 -> B7,B9)
    ISSUE_B(0, 10)                            // 12
    LOAD_A4(1, 9)  WAITV(8)  MFMA8(1, 0)      // t=7  (retire B7)
    ISSUE_B(1, 11)
    LOAD_A4(0, 10) WAITV(8)  MFMA8(2, 1)      // t=9
    ISSUE_B(2, 12)
    LOAD_A4(1, 11) WAITV(8)  MFMA8(0, 0)      // t=10
    ISSUE_B(0, 13)
    LOAD_A4(0, 12) WAITV(8)  MFMA8(1, 1)      // t=11
    ISSUE_B(1, 14)
    LOAD_A4(1, 13) WAITV(8)  MFMA8(2, 0)      // t=12
    ISSUE_B(2, 15)
    LOAD_A4(0, 14) WAITV(8)  MFMA8(0, 1)      // t=13
    ISSUE_B(0, 16)
    LOAD_A4(1, 15) WAITV(8)  MFMA8(1, 0)      // t=14
    ISSUE_B(1, 17)
    LOAD_A4(0, 16) WAITV(8)  MFMA8(2, 1)      // t=15
    ISSUE_B(2, 19)
    LOAD_A4(1, 17) WAITV(8)  MFMA8(0, 0)      // t=16
    ISSUE_B(0, 21)
    LOAD_A4(0, 19) WAITV(8)  MFMA8(1, 1)      // t=17
    ISSUE_B(1, 22)
    LOAD_A4(1, 21) WAITV(8)  MFMA8(2, 0)      // t=19
    ISSUE_B(2, 23)
    LOAD_A4(0, 22) WAITV(8)  MFMA8(0, 1)      // t=21
    ISSUE_B(0, 25)
    LOAD_A4(1, 23) WAITV(8)  MFMA8(1, 0)      // t=22
    LOAD_A4(0, 25) WAITV(4)  MFMA8(2, 1)      // t=23
                   WAITV(0)  MFMA8(0, 0)      // t=25

    // ---- epilogue: y = y0+yh*2+yy, z = z0+l15, ch = nh*32 + nt*16 + kg*4 ----
    float* obase = out + ((((size_t)(b * 32 + X) * 32 + (y0 + yh * 2)) * 32) + z0) * 64
                 + nh * 32 + kg * 4;
    *reinterpret_cast<f32x4*>(obase + l15 * 64)               = acc00;
    *reinterpret_cast<f32x4*>(obase + l15 * 64 + 16)          = acc01;
    *reinterpret_cast<f32x4*>(obase + 2048 + l15 * 64)        = acc10;
    *reinterpret_cast<f32x4*>(obase + 2048 + l15 * 64 + 16)   = acc11;
}

// ---------------------------------------------------------------------------
// Fallback (fp32 staging through VGPRs, old g_kT layout), if ws too small.
// ---------------------------------------------------------------------------
#define ZS 68
#define NROWS 408

__global__ __launch_bounds__(256, 2) void conv_mfma_fb(
    const float* __restrict__ x, float* __restrict__ out)
{
    __shared__ __align__(16) u16 xts[NROWS * ZS];
    const int bid0 = blockIdx.x;
    const int bid  = (bid0 & 7) * 256 + (bid0 >> 3);
    const int b   = bid >> 9;
    const int X   = (bid >> 4) & 31;
    const int y0  = (bid & 15) << 1;
    const int tid = threadIdx.x;

    {
        const int pr = tid >> 2;
        const int q  = tid & 3;
#pragma unroll
        for (int pass = 0; pass < 7; ++pass) {
            const int idx = pass * 64 + pr;
            if (idx < NROWS) {
                const int rid = idx / 34;
                const int zid = idx - rid * 34;
                const int xin = X + (rid >> 2) - 1;
                const int yin = y0 + (rid & 3) - 1;
                const int zin = zid - 1;
                u32x4 p0 = {0u,0u,0u,0u}, p1 = {0u,0u,0u,0u};
                if ((unsigned)xin < 32u && (unsigned)yin < 32u && (unsigned)zin < 32u) {
                    const float4* src = reinterpret_cast<const float4*>(
                        x + ((((b * 32 + xin) * 32 + yin) * 32 + zin) * 64 + q * 16));
                    float4 v0 = src[0], v1 = src[1], v2 = src[2], v3 = src[3];
                    p0[0] = pack_bf(v0.x, v0.y); p0[1] = pack_bf(v0.z, v0.w);
                    p0[2] = pack_bf(v1.x, v1.y); p0[3] = pack_bf(v1.z, v1.w);
                    p1[0] = pack_bf(v2.x, v2.y); p1[1] = pack_bf(v2.z, v2.w);
                    p1[2] = pack_bf(v3.x, v3.y); p1[3] = pack_bf(v3.z, v3.w);
                }
                u16* dst = &xts[idx * ZS + q * 16];
                *reinterpret_cast<u32x4*>(dst)     = p0;
                *reinterpret_cast<u32x4*>(dst + 8) = p1;
            }
        }
    }
    __syncthreads();

    const int w    = tid >> 6;
    const int lane = tid & 63;
    const int l15  = lane & 15;
    const int kg   = lane >> 4;
    const int mh   = w >> 1;
    const int nh   = w & 1;
    const int chb  = kg * 8;

    const u16* abase = &xts[l15 * ZS + chb];
    const u16* bbase = &g_kT[(nh * 32 + l15) * 64 + chb];

    const f32x4 z4 = {0.f, 0.f, 0.f, 0.f};
    f32x4 acc[2][2] = {{z4, z4}, {z4, z4}};

    constexpr int NT = 19;
    constexpr int TAPS[NT] = {1,3,4,5,7,9,10,11,12,13,14,15,16,17,19,21,22,23,25};

#pragma unroll
    for (int ti = 0; ti < NT; ++ti) {
        const int t = TAPS[ti];
        const int dxt = t / 9, dyt = (t / 3) % 3, dzt = t % 3;
        const int rid = dxt * 4 + mh + dyt;
        bf16x8 bfr[4], afr[4];
#pragma unroll
        for (int kb = 0; kb < 2; ++kb)
#pragma unroll
        for (int nt = 0; nt < 2; ++nt)
            bfr[kb*2+nt] = *reinterpret_cast<const bf16x8*>(
                bbase + (t * 64 + nt * 16) * 64 + kb * 32);
#pragma unroll
        for (int kb = 0; kb < 2; ++kb)
#pragma unroll
        for (int mt = 0; mt < 2; ++mt)
            afr[kb*2+mt] = *reinterpret_cast<const bf16x8*>(
                abase + (rid * 34 + dzt + mt * 16) * ZS + kb * 32);
#pragma unroll
        for (int kb = 0; kb < 2; ++kb)
#pragma unroll
        for (int mt = 0; mt < 2; ++mt)
#pragma unroll
        for (int nt = 0; nt < 2; ++nt)
            acc[mt][nt] = __builtin_amdgcn_mfma_f32_16x16x32_bf16(
                bfr[kb*2+nt], afr[kb*2+mt], acc[mt][nt], 0, 0, 0);
    }

    float* obase = out + (((b * 32 + X) * 32 + (y0 + mh)) * 32) * 64 + nh * 32 + kg * 4;
#pragma unroll
    for (int mt = 0; mt < 2; ++mt)
#pragma unroll
        for (int nt = 0; nt < 2; ++nt) {
            float4 v;
            v.x = acc[mt][nt][0]; v.y = acc[mt][nt][1];
            v.z = acc[mt][nt][2]; v.w = acc[mt][nt][3];
            *reinterpret_cast<float4*>(obase + (mt * 16 + l15) * 64 + nt * 16) = v;
        }
}

extern "C" void kernel_launch(void* const* d_in, const int* in_sizes, int n_in,
                              void* d_out, int out_size, void* d_ws, size_t ws_size,
                              hipStream_t stream)
{
    const float* x    = (const float*)d_in[0];
    const float* Wsc0 = (const float*)d_in[1];
    const float* Wsc1 = (const float*)d_in[2];
    const float* w1   = (const float*)d_in[3];
    const float* w2   = (const float*)d_in[4];
    const float* w3   = (const float*)d_in[5];
    const float* w4   = (const float*)d_in[6];
    float* out = (float*)d_out;

    const size_t xb_bytes = (size_t)4 * 32 * 32 * 32 * 64 * 2;   // 16.8 MB
    if (ws_size >= 4096 + xb_bytes) {
        u32* zp = (u32*)d_ws;
        u16* xb = (u16*)((char*)d_ws + 4096);
        prep<<<dim3(27 + 4096), dim3(256), 0, stream>>>(Wsc0, Wsc1, w1, w2, w3, w4,
                                                        x, xb, zp);
        conv_mfma7<<<dim3(2048), dim3(256), 0, stream>>>(xb, zp, out);
    } else {
        prep<<<dim3(27), dim3(256), 0, stream>>>(Wsc0, Wsc1, w1, w2, w3, w4,
                                                 x, (u16*)nullptr, (u32*)nullptr);
        conv_mfma_fb<<<dim3(2048), dim3(256), 0, stream>>>(x, out);
    }
}